// Round 7
// baseline (16074.788 us; speedup 1.0000x reference)
//
#include <hip/hip_runtime.h>

// ---------------------------------------------------------------------------
// ResRNN: sequential gated residual RNN, B=64, T=2048, D=32, H=256 (fp32).
//
// R12 == R11 resubmission (R11 died on container acquisition, same infra
// signature as Round 0 which passed on resubmit; kernel unchanged to keep
// the A/B clean).
//
// R11: R5 (proven 13817us) + proxy-gated polling (contention reduction).
//  * R8-R10 post-mortem: all three same-XCD/sc0 protocol variants died in
//    harness with no device data; the sc0 cross-wg protocol is the common
//    element and cannot be proven hang-free (stale clean L2 lines can pin).
//    Crews abandoned per R10 pre-commitment. Device-scope (sc0 sc1)
//    everywhere, R5 topology: 64 RNN wgs (4 row-groups x 16 col-slices,
//    weights in LDS 89KB/CU) + 4 out-wgs, depth-32 rings, tagged
//    self-validating payload words (tag<<16|bf16), 2-hop critical cycle,
//    h1 lookahead one step ahead.
//  * R11 change: every poll attempt was 16x dwordx4 with lanes 1KB apart =
//    1024 line transactions per wg-attempt; 68 wgs spinning = heavy
//    coherence-point contention (model hop ~1.1us vs measured ~3.3us).
//    Now each spin is gated by a 1-dword-per-lane PROXY poll (lane polls
//    dword (nn&7)*32 into its row -> wave-wide coverage of all 16 producer
//    slices); the full 16x dwordx4 read + per-dword tag validation happens
//    only after proxies pass. Spin traffic /16; correctness identical
//    (proxy pass is implied by the old exit condition; full read still
//    validates every dword before use).
// ---------------------------------------------------------------------------

#define T_LEN 2048
#define BATCH 64
#define DIM   32
#define HID   256
#define NRG   4
#define RING  32

typedef short    frag_ab __attribute__((ext_vector_type(8)));   // 8 x bf16
typedef float    frag_cd __attribute__((ext_vector_type(4)));   // 4 x f32
typedef float    float4v __attribute__((ext_vector_type(4)));
typedef unsigned uint4v  __attribute__((ext_vector_type(4)));

#define MFMA16(a, b, c) __builtin_amdgcn_mfma_f32_16x16x32_bf16((a), (b), (c), 0, 0, 0)

// LDS slot bases (1 slot = one K-tile of B-frags = 64 lanes * 16 B = 1 KB)
#define S_W1 0
#define S_U1 1
#define S_W2 9
#define S_U2 17
#define S_W3 25
#define S_U3 33
#define S_V3 41
#define S_G1 49   // 49..56 h1-part, 57..64 h2-part
#define S_G2 65   // 65..72 h1, 73..80 h2, 81..88 h3
#define NSLOT 89
#define LDS_BYTES (NSLOT * 64 * 16)   // 91,136 B

// workspace layout
#define H1_OFF   0
#define H1_SZ    (2 * BATCH * HID * 4)              // 128 KB (2-deep)
#define H2R_OFF  (H1_OFF + H1_SZ)
#define H2R_SZ   (RING * BATCH * HID * 4)           // 2 MB
#define H3R_OFF  (H2R_OFF + H2R_SZ)
#define H3R_SZ   (RING * BATCH * HID * 4)           // 2 MB
#define CTL_OFF  (H3R_OFF + H3R_SZ)
#define CTL_SZ   (NRG * 16 * 4)                     // done[rg] pad 16 dw

__device__ __forceinline__ unsigned short f2bf(float f) {
  unsigned u = __builtin_bit_cast(unsigned, f);
  u = (u + 0x7FFFu + ((u >> 16) & 1u)) >> 16;   // RNE
  return (unsigned short)u;
}

__device__ __forceinline__ float fast_tanh(float x) {
  x = fminf(fmaxf(x, -15.f), 15.f);
  float e = __expf(2.f * x);
  return (e - 1.f) / (e + 1.f);
}

__device__ __forceinline__ float fast_sigmoid(float x) {
  x = fminf(fmaxf(x, -30.f), 30.f);
  return 1.f / (1.f + __expf(-x));
}

// ---- LLC-visible memory ops (sc0 sc1) ----
__device__ __forceinline__ void st_sys_u32(unsigned* p, unsigned v) {
  asm volatile("global_store_dword %0, %1, off sc0 sc1" :: "v"(p), "v"(v) : "memory");
}
__device__ __forceinline__ unsigned ld_sys_u32(const unsigned* p) {
  unsigned r;
  asm volatile("global_load_dword %0, %1, off sc0 sc1\n\t"
               "s_waitcnt vmcnt(0)"
               : "=v"(r) : "v"(p) : "memory");
  return r;
}

// one-shot payload read: 16 x dwordx4 (sc0 sc1) pipelined, single vmcnt.
// p = base + row*HID + quad*8 (dwords); offsets kt*128 + {0,16} bytes.
__device__ __forceinline__ void load16_sys(const unsigned* p, uint4v r[16]) {
  asm volatile(
      "global_load_dwordx4 %0, %16, off sc0 sc1\n\t"
      "global_load_dwordx4 %1, %16, off offset:16 sc0 sc1\n\t"
      "global_load_dwordx4 %2, %16, off offset:128 sc0 sc1\n\t"
      "global_load_dwordx4 %3, %16, off offset:144 sc0 sc1\n\t"
      "global_load_dwordx4 %4, %16, off offset:256 sc0 sc1\n\t"
      "global_load_dwordx4 %5, %16, off offset:272 sc0 sc1\n\t"
      "global_load_dwordx4 %6, %16, off offset:384 sc0 sc1\n\t"
      "global_load_dwordx4 %7, %16, off offset:400 sc0 sc1\n\t"
      "global_load_dwordx4 %8, %16, off offset:512 sc0 sc1\n\t"
      "global_load_dwordx4 %9, %16, off offset:528 sc0 sc1\n\t"
      "global_load_dwordx4 %10, %16, off offset:640 sc0 sc1\n\t"
      "global_load_dwordx4 %11, %16, off offset:656 sc0 sc1\n\t"
      "global_load_dwordx4 %12, %16, off offset:768 sc0 sc1\n\t"
      "global_load_dwordx4 %13, %16, off offset:784 sc0 sc1\n\t"
      "global_load_dwordx4 %14, %16, off offset:896 sc0 sc1\n\t"
      "global_load_dwordx4 %15, %16, off offset:912 sc0 sc1\n\t"
      "s_waitcnt vmcnt(0)"
      : "=v"(r[0]), "=v"(r[1]), "=v"(r[2]), "=v"(r[3]),
        "=v"(r[4]), "=v"(r[5]), "=v"(r[6]), "=v"(r[7]),
        "=v"(r[8]), "=v"(r[9]), "=v"(r[10]), "=v"(r[11]),
        "=v"(r[12]), "=v"(r[13]), "=v"(r[14]), "=v"(r[15])
      : "v"(p)
      : "memory");
}

__device__ __forceinline__ bool unpack_check(const uint4v r[16], unsigned tag16, frag_ab* a) {
  bool ok = true;
  #pragma unroll
  for (int kt = 0; kt < 8; ++kt) {
    #pragma unroll
    for (int j = 0; j < 8; ++j) {
      unsigned w = r[kt * 2 + (j >> 2)][j & 3];
      ok &= ((w >> 16) == tag16);
      a[kt][j] = (short)w;
    }
  }
  return ok;
}

// proxy-gated poll: spin on ONE dword/lane (wave covers all 16 producer
// slices via (nn&7)-spread k-tiles), then full validated payload read.
__device__ __forceinline__ void read_state(const unsigned* p, unsigned proxy_off,
                                           unsigned tag16, frag_ab* a) {
  const unsigned* pp = p + proxy_off;
  while (!__all((ld_sys_u32(pp) >> 16) == tag16)) {}
  for (;;) {
    uint4v r[16];
    load16_sys(p, r);
    if (__all(unpack_check(r, tag16, a))) return;
  }
}

// publish 4 tagged payload words (rows rr at stride HID), fire-and-forget
__device__ __forceinline__ void publish4(unsigned* pp, unsigned tag16, const float* v) {
  #pragma unroll
  for (int rr = 0; rr < 4; ++rr)
    st_sys_u32(pp + (size_t)rr * HID, (tag16 << 16) | (unsigned)f2bf(v[rr]));
}

__global__ void __launch_bounds__(64, 1)
resrnn_kernel(const float* __restrict__ x,
              const float* __restrict__ W1, const float* __restrict__ U1, const float* __restrict__ b1,
              const float* __restrict__ W2, const float* __restrict__ U2, const float* __restrict__ b2,
              const float* __restrict__ W3, const float* __restrict__ U3, const float* __restrict__ V3,
              const float* __restrict__ b3,
              const float* __restrict__ G1, const float* __restrict__ bg1,
              const float* __restrict__ G2, const float* __restrict__ bg2,
              const float* __restrict__ O1, const float* __restrict__ O2, const float* __restrict__ bo,
              float* __restrict__ out,
              unsigned* __restrict__ h1buf,   // [2][BATCH][HID] tagged
              unsigned* __restrict__ h2r,     // [RING][BATCH][HID] tagged
              unsigned* __restrict__ h3r,     // [RING][BATCH][HID] tagged
              unsigned* __restrict__ done)    // [NRG] pad16, monotonic
{
  extern __shared__ char smem[];
  frag_ab* wf = (frag_ab*)smem;

  const int lane = (int)threadIdx.x;   // block = 1 wave of 64
  const int quad = lane >> 4;
  const int nn   = lane & 15;
  const int bid  = (int)blockIdx.x;

  // proxy offset within a lane's row: k-tile (nn&7) -> dword (nn&7)*32
  const unsigned pxo = (unsigned)((nn & 7) * 32);

  if (bid < 64) {
    // ------------------------- RNN workgroup -------------------------
    const int rg = bid & 3;
    const int sl = bid >> 2;
    const int colbase = sl * 16;

    // ---- stage weights into LDS as bf16 B-fragments ----
    {
      const float* mats[9] = { W1, U1, W2, U2, W3, U3, V3, G1, G2 };
      const int    nkt[9]  = { 1, 8, 8, 8, 8, 8, 8, 16, 24 };
      int slot = 0;
      for (int m = 0; m < 9; ++m) {
        const float* W = mats[m];
        for (int kt = 0; kt < nkt[m]; ++kt) {
          frag_ab f;
          #pragma unroll
          for (int j = 0; j < 8; ++j) {
            int k = kt * 32 + quad * 8 + j;
            f[j] = (short)f2bf(W[(size_t)k * HID + colbase + nn]);
          }
          wf[slot * 64 + lane] = f;
          ++slot;
        }
      }
    }

    const float b1l  = b1[colbase + nn];
    const float b2l  = b2[colbase + nn];
    const float b3l  = b3[colbase + nn];
    const float bg1l = bg1[colbase + nn];
    const float bg2l = bg2[colbase + nn];

    const frag_ab zf = {0,0,0,0,0,0,0,0};
    frag_ab a1n[8], a3old[8];
    #pragma unroll
    for (int i = 0; i < 8; ++i) { a1n[i] = zf; a3old[i] = zf; }
    float h2l[4] = {0.f,0.f,0.f,0.f};
    float h3l[4] = {0.f,0.f,0.f,0.f};
    float z1l[4] = {1.f,1.f,1.f,1.f};
    float z2l[4] = {1.f,1.f,1.f,1.f};

    const float*    xrow  = x + (size_t)(rg * 16 + nn) * T_LEN * DIM + quad * 8;
    unsigned*       h1pub = h1buf + ((size_t)(rg * 16 + quad * 4)) * HID + colbase + nn;
    const unsigned* h1rd  = h1buf + ((size_t)(rg * 16 + nn)) * HID + quad * 8;
    const size_t    h1st  = (size_t)BATCH * HID;   // slot stride (dwords)

    // ---- prologue: h1(0) = tanh(x(0)@W1 + b1), publish slot0 tag1 ----
    {
      frag_cd p = {0.f,0.f,0.f,0.f};
      float4v xa = *(const float4v*)xrow;
      float4v xb = *(const float4v*)(xrow + 4);
      frag_ab xf;
      #pragma unroll
      for (int j = 0; j < 4; ++j) { xf[j] = (short)f2bf(xa[j]); xf[4 + j] = (short)f2bf(xb[j]); }
      p = MFMA16(xf, wf[S_W1 * 64 + lane], p);
      float v[4];
      #pragma unroll
      for (int rr = 0; rr < 4; ++rr) v[rr] = fast_tanh(p[rr] + b1l);
      publish4(h1pub, 1u, v);
    }
    read_state(h1rd, pxo, 1u, a1n);          // a1n = h1(0)

    // p2acc = W2@h1(0) + U2@h2(-1=0)
    frag_cd p2a = {0.f,0.f,0.f,0.f}, p2b = {0.f,0.f,0.f,0.f};
    #pragma unroll
    for (int kt = 0; kt < 4; ++kt) p2a = MFMA16(a1n[kt], wf[(S_W2 + kt) * 64 + lane], p2a);
    #pragma unroll
    for (int kt = 4; kt < 8; ++kt) p2b = MFMA16(a1n[kt], wf[(S_W2 + kt) * 64 + lane], p2b);

    for (int t = 0; t < T_LEN; ++t) {
      const unsigned tag  = (unsigned)(t + 1);
      const int      slot = t & (RING - 1);

      // amortized ring back-pressure: cover slots for steps t..t+7
      if (t >= RING && (t & 7) == 0) {
        const unsigned need = (unsigned)(t - RING + 8);
        while (ld_sys_u32(done + rg * 16) < need) {}
      }

      // ---- 1. h2(t) update + publish (p2acc ready, z1 from gates(t-1)) ----
      #pragma unroll
      for (int rr = 0; rr < 4; ++rr) {
        float c = fast_tanh(p2a[rr] + p2b[rr] + b2l);
        h2l[rr] = z1l[rr] * c + (1.f - z1l[rr]) * h2l[rr];
      }
      publish4(h2r + ((size_t)slot * BATCH + rg * 16 + quad * 4) * HID + colbase + nn, tag, h2l);

      // ---- 2. h1 lookahead: h1(t+1) = tanh(x(t+1)@W1 + U1@h1(t) + b1) ----
      if (t + 1 < T_LEN) {
        frag_cd p = {0.f,0.f,0.f,0.f};
        const float* xp = xrow + (size_t)(t + 1) * DIM;
        float4v xa = *(const float4v*)xp;
        float4v xb = *(const float4v*)(xp + 4);
        frag_ab xf;
        #pragma unroll
        for (int j = 0; j < 4; ++j) { xf[j] = (short)f2bf(xa[j]); xf[4 + j] = (short)f2bf(xb[j]); }
        p = MFMA16(xf, wf[S_W1 * 64 + lane], p);
        #pragma unroll
        for (int kt = 0; kt < 8; ++kt) p = MFMA16(a1n[kt], wf[(S_U1 + kt) * 64 + lane], p);
        float v[4];
        #pragma unroll
        for (int rr = 0; rr < 4; ++rr) v[rr] = fast_tanh(p[rr] + b1l);
        publish4(h1pub + ((size_t)((t + 1) & 1)) * h1st, tag + 1u, v);
      }

      // ---- 3. precompute (indep of h2(t), h3(t)) ----
      frag_cd p3u = {0.f,0.f,0.f,0.f}, pg1a = {0.f,0.f,0.f,0.f}, pg2a = {0.f,0.f,0.f,0.f};
      #pragma unroll
      for (int kt = 0; kt < 8; ++kt) p3u = MFMA16(a3old[kt], wf[(S_U3 + kt) * 64 + lane], p3u);
      #pragma unroll
      for (int kt = 0; kt < 8; ++kt) p3u = MFMA16(a1n[kt], wf[(S_V3 + kt) * 64 + lane], p3u);
      #pragma unroll
      for (int kt = 0; kt < 8; ++kt) pg1a = MFMA16(a1n[kt], wf[(S_G1 + kt) * 64 + lane], pg1a);
      #pragma unroll
      for (int kt = 0; kt < 8; ++kt) pg2a = MFMA16(a1n[kt], wf[(S_G2 + kt) * 64 + lane], pg2a);

      // ---- 4. poll h2(t) full (proxy-gated) ----
      frag_ab a2[8];
      read_state(h2r + ((size_t)slot * BATCH + rg * 16 + nn) * HID + quad * 8, pxo, tag, a2);

      // ---- 5. h3(t) update + publish ----
      {
        frag_cd p3 = p3u;
        #pragma unroll
        for (int kt = 0; kt < 8; ++kt) p3 = MFMA16(a2[kt], wf[(S_W3 + kt) * 64 + lane], p3);
        #pragma unroll
        for (int rr = 0; rr < 4; ++rr) {
          float c = fast_tanh(p3[rr] + b3l);
          h3l[rr] = z2l[rr] * c + (1.f - z2l[rr]) * h3l[rr];
        }
        publish4(h3r + ((size_t)slot * BATCH + rg * 16 + quad * 4) * HID + colbase + nn, tag, h3l);
      }

      // ---- 6. precompute next-iter p2acc + gate h2-parts; poll h1(t+1) ----
      frag_cd pg1b = {0.f,0.f,0.f,0.f}, pg2b = {0.f,0.f,0.f,0.f};
      #pragma unroll
      for (int kt = 0; kt < 8; ++kt) pg1b = MFMA16(a2[kt], wf[(S_G1 + 8 + kt) * 64 + lane], pg1b);
      #pragma unroll
      for (int kt = 0; kt < 8; ++kt) pg2b = MFMA16(a2[kt], wf[(S_G2 + 8 + kt) * 64 + lane], pg2b);
      p2a = (frag_cd){0.f,0.f,0.f,0.f};
      p2b = (frag_cd){0.f,0.f,0.f,0.f};
      #pragma unroll
      for (int kt = 0; kt < 4; ++kt) p2a = MFMA16(a2[kt], wf[(S_U2 + kt) * 64 + lane], p2a);
      #pragma unroll
      for (int kt = 4; kt < 8; ++kt) p2b = MFMA16(a2[kt], wf[(S_U2 + kt) * 64 + lane], p2b);
      if (t + 1 < T_LEN) {
        read_state(h1rd + ((size_t)((t + 1) & 1)) * h1st, pxo, tag + 1u, a1n);  // a1n = h1(t+1)
        #pragma unroll
        for (int kt = 0; kt < 4; ++kt) p2a = MFMA16(a1n[kt], wf[(S_W2 + kt) * 64 + lane], p2a);
        #pragma unroll
        for (int kt = 4; kt < 8; ++kt) p2b = MFMA16(a1n[kt], wf[(S_W2 + kt) * 64 + lane], p2b);
      }

      // ---- 7. poll h3(t) full (proxy-gated) ----
      read_state(h3r + ((size_t)slot * BATCH + rg * 16 + nn) * HID + quad * 8, pxo, tag, a3old);

      // ---- 8. gates(t) ----
      frag_cd pg2c = {0.f,0.f,0.f,0.f};
      #pragma unroll
      for (int kt = 0; kt < 8; ++kt) pg2c = MFMA16(a3old[kt], wf[(S_G2 + 16 + kt) * 64 + lane], pg2c);
      #pragma unroll
      for (int rr = 0; rr < 4; ++rr) {
        float z1n = fast_sigmoid(pg1a[rr] + pg1b[rr] + bg1l);
        float z2n = fast_sigmoid(pg2a[rr] + pg2b[rr] + pg2c[rr] + bg2l);
        z1l[rr] = z1n * z2n;
        z2l[rr] = z2n;
      }
    }
  } else {
    // --------------------- output-projection workgroup ---------------------
    const int rg = bid - 64;
    {
      const float* mats[2] = { O1, O2 };
      for (int m = 0; m < 2; ++m)
        for (int nt = 0; nt < 2; ++nt)
          for (int kt = 0; kt < 8; ++kt) {
            frag_ab f;
            #pragma unroll
            for (int j = 0; j < 8; ++j) {
              int k = kt * 32 + quad * 8 + j;
              f[j] = (short)f2bf(mats[m][(size_t)k * DIM + nt * 16 + nn]);
            }
            wf[(m * 16 + nt * 8 + kt) * 64 + lane] = f;
          }
    }
    const float bo0 = bo[nn];
    const float bo1 = bo[16 + nn];

    for (int t = 0; t < T_LEN; ++t) {
      const unsigned tag  = (unsigned)(t + 1);
      const int      slot = t & (RING - 1);
      const unsigned* g2p = h2r + ((size_t)slot * BATCH + rg * 16 + nn) * HID + quad * 8;
      const unsigned* g3p = h3r + ((size_t)slot * BATCH + rg * 16 + nn) * HID + quad * 8;

      // proxy-gated combined poll of h2(t), h3(t)
      while (!__all(((ld_sys_u32(g2p + pxo) >> 16) == tag) &
                    ((ld_sys_u32(g3p + pxo) >> 16) == tag))) {}

      frag_ab a2[8], a3[8];
      for (;;) {
        uint4v r2[16], r3[16];
        load16_sys(g2p, r2);
        load16_sys(g3p, r3);
        bool ok = unpack_check(r2, tag, a2);
        ok &= unpack_check(r3, tag, a3);
        if (__all(ok)) break;
      }

      frag_cd o0 = {0.f,0.f,0.f,0.f}, o1 = {0.f,0.f,0.f,0.f};
      #pragma unroll
      for (int kt = 0; kt < 8; ++kt) {
        o0 = MFMA16(a2[kt], wf[(0 * 16 + 0 * 8 + kt) * 64 + lane], o0);
        o1 = MFMA16(a2[kt], wf[(0 * 16 + 1 * 8 + kt) * 64 + lane], o1);
        o0 = MFMA16(a3[kt], wf[(1 * 16 + 0 * 8 + kt) * 64 + lane], o0);
        o1 = MFMA16(a3[kt], wf[(1 * 16 + 1 * 8 + kt) * 64 + lane], o1);
      }
      #pragma unroll
      for (int rr = 0; rr < 4; ++rr) {
        float* op = out + ((size_t)(rg * 16 + quad * 4 + rr) * T_LEN + t) * DIM;
        op[nn]      = o0[rr] + bo0;
        op[16 + nn] = o1[rr] + bo1;
      }
      // ring data consumed into registers -> free slot
      if (lane == 0) st_sys_u32(done + rg * 16, tag);
    }
  }
}

extern "C" void kernel_launch(void* const* d_in, const int* in_sizes, int n_in,
                              void* d_out, int out_size, void* d_ws, size_t ws_size,
                              hipStream_t stream)
{
  (void)in_sizes; (void)n_in; (void)out_size; (void)ws_size;

  const float* x   = (const float*)d_in[0];
  const float* W1  = (const float*)d_in[1];
  const float* U1  = (const float*)d_in[2];
  const float* b1  = (const float*)d_in[3];
  const float* W2  = (const float*)d_in[4];
  const float* U2  = (const float*)d_in[5];
  const float* b2  = (const float*)d_in[6];
  const float* W3  = (const float*)d_in[7];
  const float* U3  = (const float*)d_in[8];
  const float* V3  = (const float*)d_in[9];
  const float* b3  = (const float*)d_in[10];
  const float* G1  = (const float*)d_in[11];
  const float* bg1 = (const float*)d_in[12];
  const float* G2  = (const float*)d_in[13];
  const float* bg2 = (const float*)d_in[14];
  const float* O1  = (const float*)d_in[15];
  const float* O2  = (const float*)d_in[16];
  const float* bo  = (const float*)d_in[17];

  char* ws = (char*)d_ws;
  unsigned* h1buf = (unsigned*)(ws + H1_OFF);
  unsigned* h2r   = (unsigned*)(ws + H2R_OFF);
  unsigned* h3r   = (unsigned*)(ws + H3R_OFF);
  unsigned* done  = (unsigned*)(ws + CTL_OFF);

  // done[] must start at 0 (ws poisoned 0xAA). Tagged payload buffers need
  // no init (poison tag 0xAAAA never matches a real tag <= 2049).
  hipMemsetAsync(done, 0, CTL_SZ, stream);

  (void)hipFuncSetAttribute((const void*)resrnn_kernel,
                            hipFuncAttributeMaxDynamicSharedMemorySize, LDS_BYTES);

  resrnn_kernel<<<dim3(68), dim3(64), LDS_BYTES, stream>>>(
      x, W1, U1, b1, W2, U2, b2, W3, U3, V3, b3,
      G1, bg1, G2, bg2, O1, O2, bo,
      (float*)d_out, h1buf, h2r, h3r, done);
}

// Round 8
// 15783.507 us; speedup vs baseline: 1.0185x; 1.0185x over previous
//
#include <hip/hip_runtime.h>

// ---------------------------------------------------------------------------
// ResRNN: sequential gated residual RNN, B=64, T=2048, D=32, H=256 (fp32).
//
// R13: R5 base (inline polls, device scope) + h1 merged into the h2 ring.
//  * R12 post-mortem: proxy gating HURT (+1.1us/step) -> hop cost is serial
//    poll ROUNDS, not contention (~0.7-1.1us per serial poll event).
//  * R13: producers publish h2(t) and h1(t+1) back-to-back anyway; merge
//    them into ONE ring slot [h2(t) | h1(t+1)] with one tag. Consumer's
//    step-4 poll reads both halves under a single vmcnt -> the separate
//    h1 poll (1 of 3 serial polls/step) disappears. Numerics identical.
//  * Ordering: step-3 precompute uses a1n=h1(t) BEFORE the poll overwrites
//    it with h1(t+1); step-6 W2 part uses the new a1n. Last step publishes
//    a tagged dummy h1-half so polls terminate (values unused).
//  * RING 32->16 keeps the 2x-wide h2 ring within the proven ws footprint
//    (2MB + 1MB + 64KB). Back-pressure horizon t-8: out-wg keeps up.
//  * No new spin structure: one spin replaces two; exit condition is the
//    conjunction of two previously-proven-terminating conditions; producers
//    publish before any dependent spin (same as R5).
// ---------------------------------------------------------------------------

#define T_LEN 2048
#define BATCH 64
#define DIM   32
#define HID   256
#define NRG   4
#define RING  16
#define HALF  (BATCH * HID)   // dwords per ring half

typedef short    frag_ab __attribute__((ext_vector_type(8)));   // 8 x bf16
typedef float    frag_cd __attribute__((ext_vector_type(4)));   // 4 x f32
typedef float    float4v __attribute__((ext_vector_type(4)));
typedef unsigned uint4v  __attribute__((ext_vector_type(4)));

#define MFMA16(a, b, c) __builtin_amdgcn_mfma_f32_16x16x32_bf16((a), (b), (c), 0, 0, 0)

// LDS slot bases (1 slot = one K-tile of B-frags = 64 lanes * 16 B = 1 KB)
#define S_W1 0
#define S_U1 1
#define S_W2 9
#define S_U2 17
#define S_W3 25
#define S_U3 33
#define S_V3 41
#define S_G1 49   // 49..56 h1-part, 57..64 h2-part
#define S_G2 65   // 65..72 h1, 73..80 h2, 81..88 h3
#define NSLOT 89
#define LDS_BYTES (NSLOT * 64 * 16)   // 91,136 B

// workspace layout
#define H1_OFF   0
#define H1_SZ    (BATCH * HID * 4)                  // 64 KB (prologue only)
#define H2R_OFF  (H1_OFF + H1_SZ)
#define H2R_SZ   (RING * 2 * BATCH * HID * 4)       // 2 MB ([h2 | h1next])
#define H3R_OFF  (H2R_OFF + H2R_SZ)
#define H3R_SZ   (RING * BATCH * HID * 4)           // 1 MB
#define CTL_OFF  (H3R_OFF + H3R_SZ)
#define CTL_SZ   (NRG * 16 * 4)                     // done[rg] pad 16 dw

__device__ __forceinline__ unsigned short f2bf(float f) {
  unsigned u = __builtin_bit_cast(unsigned, f);
  u = (u + 0x7FFFu + ((u >> 16) & 1u)) >> 16;   // RNE
  return (unsigned short)u;
}

__device__ __forceinline__ float fast_tanh(float x) {
  x = fminf(fmaxf(x, -15.f), 15.f);
  float e = __expf(2.f * x);
  return (e - 1.f) / (e + 1.f);
}

__device__ __forceinline__ float fast_sigmoid(float x) {
  x = fminf(fmaxf(x, -30.f), 30.f);
  return 1.f / (1.f + __expf(-x));
}

// ---- LLC-visible memory ops (sc0 sc1) ----
__device__ __forceinline__ void st_sys_u32(unsigned* p, unsigned v) {
  asm volatile("global_store_dword %0, %1, off sc0 sc1" :: "v"(p), "v"(v) : "memory");
}
__device__ __forceinline__ unsigned ld_sys_u32(const unsigned* p) {
  unsigned r;
  asm volatile("global_load_dword %0, %1, off sc0 sc1\n\t"
               "s_waitcnt vmcnt(0)"
               : "=v"(r) : "v"(p) : "memory");
  return r;
}

// 16 x dwordx4 (sc0 sc1) pipelined; WITH trailing vmcnt(0).
#define L16BODY                                                   \
      "global_load_dwordx4 %0, %16, off sc0 sc1\n\t"              \
      "global_load_dwordx4 %1, %16, off offset:16 sc0 sc1\n\t"    \
      "global_load_dwordx4 %2, %16, off offset:128 sc0 sc1\n\t"   \
      "global_load_dwordx4 %3, %16, off offset:144 sc0 sc1\n\t"   \
      "global_load_dwordx4 %4, %16, off offset:256 sc0 sc1\n\t"   \
      "global_load_dwordx4 %5, %16, off offset:272 sc0 sc1\n\t"   \
      "global_load_dwordx4 %6, %16, off offset:384 sc0 sc1\n\t"   \
      "global_load_dwordx4 %7, %16, off offset:400 sc0 sc1\n\t"   \
      "global_load_dwordx4 %8, %16, off offset:512 sc0 sc1\n\t"   \
      "global_load_dwordx4 %9, %16, off offset:528 sc0 sc1\n\t"   \
      "global_load_dwordx4 %10, %16, off offset:640 sc0 sc1\n\t"  \
      "global_load_dwordx4 %11, %16, off offset:656 sc0 sc1\n\t"  \
      "global_load_dwordx4 %12, %16, off offset:768 sc0 sc1\n\t"  \
      "global_load_dwordx4 %13, %16, off offset:784 sc0 sc1\n\t"  \
      "global_load_dwordx4 %14, %16, off offset:896 sc0 sc1\n\t"  \
      "global_load_dwordx4 %15, %16, off offset:912 sc0 sc1"

#define L16OUTS                                                       \
      : "=v"(r[0]), "=v"(r[1]), "=v"(r[2]), "=v"(r[3]),               \
        "=v"(r[4]), "=v"(r[5]), "=v"(r[6]), "=v"(r[7]),               \
        "=v"(r[8]), "=v"(r[9]), "=v"(r[10]), "=v"(r[11]),             \
        "=v"(r[12]), "=v"(r[13]), "=v"(r[14]), "=v"(r[15])            \
      : "v"(p)                                                        \
      : "memory"

__device__ __forceinline__ void load16_sys(const unsigned* p, uint4v r[16]) {
  asm volatile(L16BODY "\n\ts_waitcnt vmcnt(0)" L16OUTS);
}
__device__ __forceinline__ void load16_nw(const unsigned* p, uint4v r[16]) {
  asm volatile(L16BODY L16OUTS);   // no wait: covered by a later vmcnt(0)
}
// ordering fence: pin reads of r AFTER the preceding vmcnt-carrying asm
__device__ __forceinline__ void order16(uint4v r[16]) {
  asm volatile("" : "+v"(r[0]), "+v"(r[1]), "+v"(r[2]), "+v"(r[3]),
                    "+v"(r[4]), "+v"(r[5]), "+v"(r[6]), "+v"(r[7]) :: "memory");
  asm volatile("" : "+v"(r[8]), "+v"(r[9]), "+v"(r[10]), "+v"(r[11]),
                    "+v"(r[12]), "+v"(r[13]), "+v"(r[14]), "+v"(r[15]) :: "memory");
}

__device__ __forceinline__ bool unpack_check(const uint4v r[16], unsigned tag16, frag_ab* a) {
  bool ok = true;
  #pragma unroll
  for (int kt = 0; kt < 8; ++kt) {
    #pragma unroll
    for (int j = 0; j < 8; ++j) {
      unsigned w = r[kt * 2 + (j >> 2)][j & 3];
      ok &= ((w >> 16) == tag16);
      a[kt][j] = (short)w;
    }
  }
  return ok;
}

// single-buffer poll (h3, prologue h1)
__device__ __forceinline__ void read_state(const unsigned* p, unsigned tag16, frag_ab* a) {
  for (;;) {
    uint4v r[16];
    load16_sys(p, r);
    if (__all(unpack_check(r, tag16, a))) return;
  }
}

// combined poll of [h2 | h1next] halves of one ring slot: 32 loads, ONE vmcnt
__device__ __forceinline__ void read_state2(const unsigned* p2, const unsigned* p1,
                                            unsigned tag16, frag_ab* a2, frag_ab* a1) {
  for (;;) {
    uint4v r1[16], r2[16];
    {
      uint4v* r = r1; const unsigned* p = p1; load16_nw(p, r);
    }
    {
      uint4v* r = r2; const unsigned* p = p2; load16_sys(p, r);  // waits both
    }
    order16(r1);
    bool ok = unpack_check(r2, tag16, a2);
    ok &= unpack_check(r1, tag16, a1);
    if (__all(ok)) return;
  }
}

// publish 4 tagged payload words (rows rr at stride HID), fire-and-forget
__device__ __forceinline__ void publish4(unsigned* pp, unsigned tag16, const float* v) {
  #pragma unroll
  for (int rr = 0; rr < 4; ++rr)
    st_sys_u32(pp + (size_t)rr * HID, (tag16 << 16) | (unsigned)f2bf(v[rr]));
}

__global__ void __launch_bounds__(64, 1)
resrnn_kernel(const float* __restrict__ x,
              const float* __restrict__ W1, const float* __restrict__ U1, const float* __restrict__ b1,
              const float* __restrict__ W2, const float* __restrict__ U2, const float* __restrict__ b2,
              const float* __restrict__ W3, const float* __restrict__ U3, const float* __restrict__ V3,
              const float* __restrict__ b3,
              const float* __restrict__ G1, const float* __restrict__ bg1,
              const float* __restrict__ G2, const float* __restrict__ bg2,
              const float* __restrict__ O1, const float* __restrict__ O2, const float* __restrict__ bo,
              float* __restrict__ out,
              unsigned* __restrict__ h1buf,   // [BATCH][HID] tagged (prologue)
              unsigned* __restrict__ h2r,     // [RING][2][BATCH][HID] tagged
              unsigned* __restrict__ h3r,     // [RING][BATCH][HID] tagged
              unsigned* __restrict__ done)    // [NRG] pad16, monotonic
{
  extern __shared__ char smem[];
  frag_ab* wf = (frag_ab*)smem;

  const int lane = (int)threadIdx.x;   // block = 1 wave of 64
  const int quad = lane >> 4;
  const int nn   = lane & 15;
  const int bid  = (int)blockIdx.x;

  if (bid < 64) {
    // ------------------------- RNN workgroup -------------------------
    const int rg = bid & 3;
    const int sl = bid >> 2;
    const int colbase = sl * 16;

    // ---- stage weights into LDS as bf16 B-fragments ----
    {
      const float* mats[9] = { W1, U1, W2, U2, W3, U3, V3, G1, G2 };
      const int    nkt[9]  = { 1, 8, 8, 8, 8, 8, 8, 16, 24 };
      int slot = 0;
      for (int m = 0; m < 9; ++m) {
        const float* W = mats[m];
        for (int kt = 0; kt < nkt[m]; ++kt) {
          frag_ab f;
          #pragma unroll
          for (int j = 0; j < 8; ++j) {
            int k = kt * 32 + quad * 8 + j;
            f[j] = (short)f2bf(W[(size_t)k * HID + colbase + nn]);
          }
          wf[slot * 64 + lane] = f;
          ++slot;
        }
      }
    }

    const float b1l  = b1[colbase + nn];
    const float b2l  = b2[colbase + nn];
    const float b3l  = b3[colbase + nn];
    const float bg1l = bg1[colbase + nn];
    const float bg2l = bg2[colbase + nn];

    const frag_ab zf = {0,0,0,0,0,0,0,0};
    frag_ab a1n[8], a3old[8];
    #pragma unroll
    for (int i = 0; i < 8; ++i) { a1n[i] = zf; a3old[i] = zf; }
    float h2l[4] = {0.f,0.f,0.f,0.f};
    float h3l[4] = {0.f,0.f,0.f,0.f};
    float z1l[4] = {1.f,1.f,1.f,1.f};
    float z2l[4] = {1.f,1.f,1.f,1.f};

    const float* xrow = x + (size_t)(rg * 16 + nn) * T_LEN * DIM + quad * 8;
    // publish base offsets (producer writes rows quad*4.., col colbase+nn)
    const size_t puboff = ((size_t)(rg * 16 + quad * 4)) * HID + colbase + nn;
    // read base offsets (consumer lane reads row nn, dwords quad*8..)
    const size_t rdoff  = ((size_t)(rg * 16 + nn)) * HID + quad * 8;

    // ---- prologue: h1(0) = tanh(x(0)@W1 + b1) via h1buf, tag 1 ----
    {
      frag_cd p = {0.f,0.f,0.f,0.f};
      float4v xa = *(const float4v*)xrow;
      float4v xb = *(const float4v*)(xrow + 4);
      frag_ab xf;
      #pragma unroll
      for (int j = 0; j < 4; ++j) { xf[j] = (short)f2bf(xa[j]); xf[4 + j] = (short)f2bf(xb[j]); }
      p = MFMA16(xf, wf[S_W1 * 64 + lane], p);
      float v[4];
      #pragma unroll
      for (int rr = 0; rr < 4; ++rr) v[rr] = fast_tanh(p[rr] + b1l);
      publish4(h1buf + puboff, 1u, v);
    }
    read_state(h1buf + rdoff, 1u, a1n);          // a1n = h1(0)

    // p2acc = W2@h1(0) + U2@h2(-1=0)
    frag_cd p2a = {0.f,0.f,0.f,0.f}, p2b = {0.f,0.f,0.f,0.f};
    #pragma unroll
    for (int kt = 0; kt < 4; ++kt) p2a = MFMA16(a1n[kt], wf[(S_W2 + kt) * 64 + lane], p2a);
    #pragma unroll
    for (int kt = 4; kt < 8; ++kt) p2b = MFMA16(a1n[kt], wf[(S_W2 + kt) * 64 + lane], p2b);

    for (int t = 0; t < T_LEN; ++t) {
      const unsigned tag  = (unsigned)(t + 1);
      const int      slot = t & (RING - 1);
      unsigned* h2slot = h2r + (size_t)slot * (2 * HALF);

      // amortized ring back-pressure: cover slots for steps t..t+7
      if (t >= RING && (t & 7) == 0) {
        const unsigned need = (unsigned)(t - RING + 8);
        while (ld_sys_u32(done + rg * 16) < need) {}
      }

      // ---- 1. h2(t) update + publish (half0) ----
      #pragma unroll
      for (int rr = 0; rr < 4; ++rr) {
        float c = fast_tanh(p2a[rr] + p2b[rr] + b2l);
        h2l[rr] = z1l[rr] * c + (1.f - z1l[rr]) * h2l[rr];
      }
      publish4(h2slot + puboff, tag, h2l);

      // ---- 2. h1 lookahead -> publish into SAME slot (half1, same tag) ----
      {
        float v[4] = {0.f, 0.f, 0.f, 0.f};
        if (t + 1 < T_LEN) {
          frag_cd p = {0.f,0.f,0.f,0.f};
          const float* xp = xrow + (size_t)(t + 1) * DIM;
          float4v xa = *(const float4v*)xp;
          float4v xb = *(const float4v*)(xp + 4);
          frag_ab xf;
          #pragma unroll
          for (int j = 0; j < 4; ++j) { xf[j] = (short)f2bf(xa[j]); xf[4 + j] = (short)f2bf(xb[j]); }
          p = MFMA16(xf, wf[S_W1 * 64 + lane], p);
          #pragma unroll
          for (int kt = 0; kt < 8; ++kt) p = MFMA16(a1n[kt], wf[(S_U1 + kt) * 64 + lane], p);
          #pragma unroll
          for (int rr = 0; rr < 4; ++rr) v[rr] = fast_tanh(p[rr] + b1l);
        }
        publish4(h2slot + HALF + puboff, tag, v);   // dummy (tagged) at last step
      }

      // ---- 3. precompute (uses a1n = h1(t), a3old = h3(t-1)) ----
      frag_cd p3u = {0.f,0.f,0.f,0.f}, pg1a = {0.f,0.f,0.f,0.f}, pg2a = {0.f,0.f,0.f,0.f};
      #pragma unroll
      for (int kt = 0; kt < 8; ++kt) p3u = MFMA16(a3old[kt], wf[(S_U3 + kt) * 64 + lane], p3u);
      #pragma unroll
      for (int kt = 0; kt < 8; ++kt) p3u = MFMA16(a1n[kt], wf[(S_V3 + kt) * 64 + lane], p3u);
      #pragma unroll
      for (int kt = 0; kt < 8; ++kt) pg1a = MFMA16(a1n[kt], wf[(S_G1 + kt) * 64 + lane], pg1a);
      #pragma unroll
      for (int kt = 0; kt < 8; ++kt) pg2a = MFMA16(a1n[kt], wf[(S_G2 + kt) * 64 + lane], pg2a);

      // ---- 4. combined poll: h2(t) AND h1(t+1) in one vmcnt round ----
      frag_ab a2[8];
      read_state2(h2slot + rdoff, h2slot + HALF + rdoff, tag, a2, a1n);
      // a1n now = h1(t+1) (garbage at t=T_LEN-1; unused then)

      // ---- 5. h3(t) update + publish ----
      {
        frag_cd p3 = p3u;
        #pragma unroll
        for (int kt = 0; kt < 8; ++kt) p3 = MFMA16(a2[kt], wf[(S_W3 + kt) * 64 + lane], p3);
        #pragma unroll
        for (int rr = 0; rr < 4; ++rr) {
          float c = fast_tanh(p3[rr] + b3l);
          h3l[rr] = z2l[rr] * c + (1.f - z2l[rr]) * h3l[rr];
        }
        publish4(h3r + (size_t)slot * HALF + puboff, tag, h3l);
      }

      // ---- 6. next-iter p2acc + gate h2-parts (a1n already fresh) ----
      frag_cd pg1b = {0.f,0.f,0.f,0.f}, pg2b = {0.f,0.f,0.f,0.f};
      #pragma unroll
      for (int kt = 0; kt < 8; ++kt) pg1b = MFMA16(a2[kt], wf[(S_G1 + 8 + kt) * 64 + lane], pg1b);
      #pragma unroll
      for (int kt = 0; kt < 8; ++kt) pg2b = MFMA16(a2[kt], wf[(S_G2 + 8 + kt) * 64 + lane], pg2b);
      p2a = (frag_cd){0.f,0.f,0.f,0.f};
      p2b = (frag_cd){0.f,0.f,0.f,0.f};
      #pragma unroll
      for (int kt = 0; kt < 4; ++kt) p2a = MFMA16(a2[kt], wf[(S_U2 + kt) * 64 + lane], p2a);
      #pragma unroll
      for (int kt = 4; kt < 8; ++kt) p2b = MFMA16(a2[kt], wf[(S_U2 + kt) * 64 + lane], p2b);
      if (t + 1 < T_LEN) {
        #pragma unroll
        for (int kt = 0; kt < 4; ++kt) p2a = MFMA16(a1n[kt], wf[(S_W2 + kt) * 64 + lane], p2a);
        #pragma unroll
        for (int kt = 4; kt < 8; ++kt) p2b = MFMA16(a1n[kt], wf[(S_W2 + kt) * 64 + lane], p2b);
      }

      // ---- 7. poll h3(t) full ----
      read_state(h3r + (size_t)slot * HALF + rdoff, tag, a3old);

      // ---- 8. gates(t) ----
      frag_cd pg2c = {0.f,0.f,0.f,0.f};
      #pragma unroll
      for (int kt = 0; kt < 8; ++kt) pg2c = MFMA16(a3old[kt], wf[(S_G2 + 16 + kt) * 64 + lane], pg2c);
      #pragma unroll
      for (int rr = 0; rr < 4; ++rr) {
        float z1n = fast_sigmoid(pg1a[rr] + pg1b[rr] + bg1l);
        float z2n = fast_sigmoid(pg2a[rr] + pg2b[rr] + pg2c[rr] + bg2l);
        z1l[rr] = z1n * z2n;
        z2l[rr] = z2n;
      }
    }
  } else {
    // --------------------- output-projection workgroup ---------------------
    const int rg = bid - 64;
    {
      const float* mats[2] = { O1, O2 };
      for (int m = 0; m < 2; ++m)
        for (int nt = 0; nt < 2; ++nt)
          for (int kt = 0; kt < 8; ++kt) {
            frag_ab f;
            #pragma unroll
            for (int j = 0; j < 8; ++j) {
              int k = kt * 32 + quad * 8 + j;
              f[j] = (short)f2bf(mats[m][(size_t)k * DIM + nt * 16 + nn]);
            }
            wf[(m * 16 + nt * 8 + kt) * 64 + lane] = f;
          }
    }
    const float bo0 = bo[nn];
    const float bo1 = bo[16 + nn];
    const size_t rdoff = ((size_t)(rg * 16 + nn)) * HID + quad * 8;

    for (int t = 0; t < T_LEN; ++t) {
      const unsigned tag  = (unsigned)(t + 1);
      const int      slot = t & (RING - 1);
      const unsigned* g2p = h2r + (size_t)slot * (2 * HALF) + rdoff;   // half0 only
      const unsigned* g3p = h3r + (size_t)slot * HALF + rdoff;

      frag_ab a2[8], a3[8];
      for (;;) {   // combined direct-payload poll of h2(t), h3(t)
        uint4v r2[16], r3[16];
        {
          uint4v* r = r2; const unsigned* p = g2p; load16_nw(p, r);
        }
        {
          uint4v* r = r3; const unsigned* p = g3p; load16_sys(p, r);  // waits both
        }
        order16(r2);
        bool ok = unpack_check(r2, tag, a2);
        ok &= unpack_check(r3, tag, a3);
        if (__all(ok)) break;
      }

      frag_cd o0 = {0.f,0.f,0.f,0.f}, o1 = {0.f,0.f,0.f,0.f};
      #pragma unroll
      for (int kt = 0; kt < 8; ++kt) {
        o0 = MFMA16(a2[kt], wf[(0 * 16 + 0 * 8 + kt) * 64 + lane], o0);
        o1 = MFMA16(a2[kt], wf[(0 * 16 + 1 * 8 + kt) * 64 + lane], o1);
        o0 = MFMA16(a3[kt], wf[(1 * 16 + 0 * 8 + kt) * 64 + lane], o0);
        o1 = MFMA16(a3[kt], wf[(1 * 16 + 1 * 8 + kt) * 64 + lane], o1);
      }
      #pragma unroll
      for (int rr = 0; rr < 4; ++rr) {
        float* op = out + ((size_t)(rg * 16 + quad * 4 + rr) * T_LEN + t) * DIM;
        op[nn]      = o0[rr] + bo0;
        op[16 + nn] = o1[rr] + bo1;
      }
      // ring data consumed into registers -> free slot
      if (lane == 0) st_sys_u32(done + rg * 16, tag);
    }
  }
}

extern "C" void kernel_launch(void* const* d_in, const int* in_sizes, int n_in,
                              void* d_out, int out_size, void* d_ws, size_t ws_size,
                              hipStream_t stream)
{
  (void)in_sizes; (void)n_in; (void)out_size; (void)ws_size;

  const float* x   = (const float*)d_in[0];
  const float* W1  = (const float*)d_in[1];
  const float* U1  = (const float*)d_in[2];
  const float* b1  = (const float*)d_in[3];
  const float* W2  = (const float*)d_in[4];
  const float* U2  = (const float*)d_in[5];
  const float* b2  = (const float*)d_in[6];
  const float* W3  = (const float*)d_in[7];
  const float* U3  = (const float*)d_in[8];
  const float* V3  = (const float*)d_in[9];
  const float* b3  = (const float*)d_in[10];
  const float* G1  = (const float*)d_in[11];
  const float* bg1 = (const float*)d_in[12];
  const float* G2  = (const float*)d_in[13];
  const float* bg2 = (const float*)d_in[14];
  const float* O1  = (const float*)d_in[15];
  const float* O2  = (const float*)d_in[16];
  const float* bo  = (const float*)d_in[17];

  char* ws = (char*)d_ws;
  unsigned* h1buf = (unsigned*)(ws + H1_OFF);
  unsigned* h2r   = (unsigned*)(ws + H2R_OFF);
  unsigned* h3r   = (unsigned*)(ws + H3R_OFF);
  unsigned* done  = (unsigned*)(ws + CTL_OFF);

  // done[] must start at 0 (ws poisoned 0xAA). Tagged payload buffers need
  // no init (poison tag 0xAAAA never matches a real tag <= 2048).
  hipMemsetAsync(done, 0, CTL_SZ, stream);

  (void)hipFuncSetAttribute((const void*)resrnn_kernel,
                            hipFuncAttributeMaxDynamicSharedMemorySize, LDS_BYTES);

  resrnn_kernel<<<dim3(68), dim3(64), LDS_BYTES, stream>>>(
      x, W1, U1, b1, W2, U2, b2, W3, U3, V3, b3,
      G1, bg1, G2, bg2, O1, O2, bo,
      (float*)d_out, h1buf, h2r, h3r, done);
}